// Round 1
// 189.348 us; speedup vs baseline: 1.0834x; 1.0834x over previous
//
#include <hip/hip_runtime.h>
#include <math.h>

// Problem: B=16, LQ=1024, LK=1024, DK=256, DV=256, fp32 in/out, mask int32.
// Identity: softmax_k(q_s + k_s with mask) == mask-weighted softmax of k_s alone
// (q_s cancels; masked entries are exactly -1e9 -> weight 0). query never read.
// k_s ~ N(0,256) => softmax mass concentrates in top ~30-60 keys; walk an
// approximately-descending list in 64-wide chunks until provable remaining
// mass <= 1e-5 * Z.
//
// R1 change: bitonic sort_kernel (16 blocks, ~130 full-block barriers, ~110us
// inferred) replaced by a counting-sort select_kernel. attn only needs (a) a
// bucket-descending order and (b) EXACT suffix masses at the 16 chunk
// boundaries, both of which counting sort by floor(m - v) provides in ~30
// cheap barrier passes.

#define NB     16
#define NL     1024     // LQ == LK
#define ND     256      // DK == DV
#define NSTAGE 56       // top-K value rows staged in LDS (56 KB)
#define NBKT   128      // buckets of width 1.0 in log-space; e-ratio <= e per bucket

// ---------------- Kernel A: ks[b,k] = dot(key[b,k,:], w) -----------------
__global__ __launch_bounds__(256)
void ks_kernel(const float* __restrict__ key, const float* __restrict__ w,
               float* __restrict__ ks) {
    int wid  = threadIdx.x >> 6;
    int lane = threadIdx.x & 63;
    int row  = blockIdx.x * 4 + wid;               // 0 .. NB*NL-1
    const float4* krow = (const float4*)(key + (size_t)row * ND);
    float4 kv = krow[lane];
    float4 wv = ((const float4*)w)[lane];
    float p = kv.x * wv.x + kv.y * wv.y + kv.z * wv.z + kv.w * wv.w;
    #pragma unroll
    for (int off = 32; off > 0; off >>= 1)
        p += __shfl_xor(p, off, 64);
    if (lane == 0) ks[row] = p;
}

// ------- Kernel B: per batch: max, e=exp(ks-m), counting sort by -------
// ------- bucket floor(m-v), exact suffix mass at chunk boundaries -------
// Order within a bucket is arbitrary (weights differ by <= e), which is fine:
// attn processes whole 64-entry chunks and breaks on the EXACT remaining-mass
// bound rem[], computed here from the actual gathered order.
__global__ __launch_bounds__(1024)
void select_kernel(const float* __restrict__ ks,
                   float* __restrict__ e_s, int* __restrict__ idx_s,
                   float* __restrict__ rem) {
    __shared__ float red[NL];      // max-reduce scratch
    __shared__ float se[NL];       // gathered e values (bucket order)
    __shared__ int   cnt[NBKT];    // histogram
    __shared__ int   cur[NBKT];    // scan -> scatter cursors
    __shared__ float csum[16];     // per-chunk sums
    const int b = blockIdx.x;
    const int t = threadIdx.x;
    const int lane = t & 63;
    const int wid  = t >> 6;

    float v = ks[b * NL + t];

    // block max
    red[t] = v;
    __syncthreads();
    for (int off = 512; off > 0; off >>= 1) {
        if (t < off) red[t] = fmaxf(red[t], red[t + off]);
        __syncthreads();
    }
    const float m = red[0];
    __syncthreads();

    const float e = __expf(v - m);          // e in (0,1]

    // histogram of bucket = clamp(floor(m - v), 0, NBKT-1)
    if (t < NBKT) cnt[t] = 0;
    __syncthreads();
    int bkt = (int)fminf(m - v, (float)(NBKT - 1));   // m - v >= 0
    atomicAdd(&cnt[bkt], 1);
    __syncthreads();

    // inclusive scan of cnt (Hillis-Steele over 128 entries)
    if (t < NBKT) cur[t] = cnt[t];
    __syncthreads();
    for (int off = 1; off < NBKT; off <<= 1) {
        int add = 0;
        if (t < NBKT && t >= off) add = cur[t - off];
        __syncthreads();
        if (t < NBKT) cur[t] += add;
        __syncthreads();
    }
    // exclusive prefix -> scatter cursor base
    if (t < NBKT) cur[t] -= cnt[t];
    __syncthreads();

    // scatter (bijective: every t gets a unique p in [0, NL))
    int p = atomicAdd(&cur[bkt], 1);
    se[p] = e;
    e_s  [b * NL + p] = e;
    idx_s[b * NL + p] = t;
    __syncthreads();

    // per-chunk sums: wave w reduces chunk w (64 entries)
    float s = se[wid * 64 + lane];
    #pragma unroll
    for (int off = 32; off > 0; off >>= 1)
        s += __shfl_xor(s, off, 64);
    if (lane == 0) csum[wid] = s;
    __syncthreads();

    // suffix masses at the 16 boundary slots attn actually reads:
    // rem[b*NL + c*64 + 63] = sum of chunk sums for chunks > c
    if (t == 0) {
        float run = 0.0f;
        for (int c = 15; c >= 0; --c) {
            rem[b * NL + c * 64 + 63] = run;
            run += csum[c];
        }
    }
}

// ---------------- Kernel C: out[b,q,:] = sum_k p * value[b,k,:] ----------
// Block = 1024 threads = 16 waves = 16 q-rows (same batch). LDS stages the
// top-NSTAGE value rows + per-row mask bitmask + top-64 (e,idx). Chunked
// walk: 64 entries per chunk, break checked once per chunk via rem[] --
// processing extra entries past the exact break point only adds accuracy.
__global__ __launch_bounds__(1024)
void attn_kernel(const float* __restrict__ value, const int* __restrict__ mask,
                 const float* __restrict__ e_s, const int* __restrict__ idx_s,
                 const float* __restrict__ rem, float* __restrict__ out) {
    __shared__ float          lds_V[NSTAGE * ND];   // 56 KB
    __shared__ unsigned short mbits[16][64];        // 2 KB: 1024 mask bits/row
    __shared__ float          lds_e[64];
    __shared__ int            lds_idx[64];

    const int wid  = threadIdx.x >> 6;
    const int lane = threadIdx.x & 63;
    const int row  = blockIdx.x * 16 + wid;   // 0 .. NB*NL-1 (16 rows, same b)
    const int b    = row >> 10;
    const int base = b << 10;

    if (threadIdx.x < 64) {
        lds_e[threadIdx.x]   = e_s[base + threadIdx.x];
        lds_idx[threadIdx.x] = idx_s[base + threadIdx.x];
    }
    __syncthreads();

    const float4* vbase = (const float4*)(value + ((size_t)b << 10) * ND);

    // stage top-NSTAGE value rows (coalesced 1 KB per wave-row)
    for (int r = wid; r < NSTAGE; r += 16)
        ((float4*)lds_V)[r * 64 + lane] = vbase[(size_t)lds_idx[r] * 64 + lane];

    // mask row -> bits: lane owns ints [lane*16, lane*16+16)
    const int4* mrow4 = (const int4*)(mask + (size_t)row * NL);
    unsigned int bits = 0;
    #pragma unroll
    for (int j = 0; j < 4; ++j) {
        int4 m = mrow4[lane * 4 + j];
        bits |= (m.x != 0 ? 1u : 0u) << (j * 4 + 0);
        bits |= (m.y != 0 ? 1u : 0u) << (j * 4 + 1);
        bits |= (m.z != 0 ? 1u : 0u) << (j * 4 + 2);
        bits |= (m.w != 0 ? 1u : 0u) << (j * 4 + 3);
    }
    mbits[wid][lane] = (unsigned short)bits;
    __syncthreads();

    float4 acc = make_float4(0.f, 0.f, 0.f, 0.f);
    float Z = 0.0f;

    // chunk 0: entries [0,64), V from LDS for i < NSTAGE
    #pragma unroll 8
    for (int i = 0; i < 64; ++i) {
        int k = lds_idx[i];
        if ((mbits[wid][k >> 4] >> (k & 15)) & 1) {
            float ei = lds_e[i];
            Z += ei;
            float4 v;
            if (i < NSTAGE) v = ((const float4*)lds_V)[i * 64 + lane];
            else            v = vbase[(size_t)k * 64 + lane];
            acc.x += ei * v.x; acc.y += ei * v.y;
            acc.z += ei * v.z; acc.w += ei * v.w;
        }
    }
    bool done = (rem[base + 63] <= 1e-5f * Z);   // Z==0 -> rem>0 -> continue

    // chunks 1..15 (rare): lane-staged entries broadcast via shuffle
    for (int c = 1; c < 16 && !done; ++c) {
        const int o = base + c * 64;
        float e_r = e_s[o + lane];
        int   k_r = idx_s[o + lane];
        #pragma unroll 8
        for (int i = 0; i < 64; ++i) {
            int k = __shfl(k_r, i);
            if ((mbits[wid][k >> 4] >> (k & 15)) & 1) {
                float ei = __shfl(e_r, i);
                Z += ei;
                float4 v = vbase[(size_t)k * 64 + lane];
                acc.x += ei * v.x; acc.y += ei * v.y;
                acc.z += ei * v.z; acc.w += ei * v.w;
            }
        }
        done = (rem[o + 63] <= 1e-5f * Z);
    }

    float4* orow = (float4*)(out + (size_t)row * ND);
    if (Z > 0.0f) {
        float inv = 1.0f / Z;
        orow[lane] = make_float4(acc.x * inv, acc.y * inv, acc.z * inv, acc.w * inv);
    } else {
        // all-masked row: reference softmax over constant -1e9 -> uniform avg
        float4 s = make_float4(0.f, 0.f, 0.f, 0.f);
        for (int k = 0; k < NL; ++k) {
            float4 v = vbase[(size_t)k * 64 + lane];
            s.x += v.x; s.y += v.y; s.z += v.z; s.w += v.w;
        }
        const float inv = 1.0f / (float)NL;
        orow[lane] = make_float4(s.x * inv, s.y * inv, s.z * inv, s.w * inv);
    }
}

extern "C" void kernel_launch(void* const* d_in, const int* in_sizes, int n_in,
                              void* d_out, int out_size, void* d_ws, size_t ws_size,
                              hipStream_t stream) {
    // setup_inputs order: query, key, value, w, mask   (query unused!)
    const float* key   = (const float*)d_in[1];
    const float* value = (const float*)d_in[2];
    const float* w     = (const float*)d_in[3];
    const int*   mask  = (const int*)d_in[4];
    float*       outp  = (float*)d_out;

    float* ks    = (float*)d_ws;                 // 16*1024 f32
    float* e_s   = ks + NB * NL;                 // 16*1024 f32 (bucket-desc order)
    int*   idx_s = (int*)(e_s + NB * NL);        // 16*1024 i32
    float* rem   = (float*)(idx_s + NB * NL);    // 16*1024 f32 suffix masses

    ks_kernel    <<<NB * NL / 4, 256, 0, stream>>>(key, w, ks);
    select_kernel<<<NB, 1024, 0, stream>>>(ks, e_s, idx_s, rem);
    attn_kernel  <<<NB * NL / 16, 1024, 0, stream>>>(value, mask, e_s, idx_s, rem, outp);
}